// Round 1
// 96.823 us; speedup vs baseline: 1.0340x; 1.0340x over previous
//
#include <hip/hip_runtime.h>

// Problem constants: B=16 batches, A=5 agents, C=512 channels, H=W=16.
#define NB 16
#define NA 5
#define NC 512
#define HW 256        // 16*16
#define NBLK 2048     // 8 blocks/CU worth of grid; items via stride
#define NTOT 5120     // 5*16*64 8-channel items

typedef _Float16 h8 __attribute__((ext_vector_type(8)));   // 16 B = one ds_read_b128

static __device__ __forceinline__ h8 splat8(float v) {
    const _Float16 h = (_Float16)v;
    h8 r = {h, h, h, h, h, h, h, h};
    return r;
}

// Force wave-uniform values into SGPRs (trans rows depend only on blockIdx-derived
// indices; keeping them scalar frees ~64 VGPRs vs f4 staging and moves the
// pair-uniform stage-2 weight math onto the scalar pipe).
static __device__ __forceinline__ float rfl(float v) {
    return __builtin_bit_cast(float,
        __builtin_amdgcn_readfirstlane(__builtin_bit_cast(int, v)));
}

struct Item {
    int i, b, c0, n;      // all wave-uniform -> SGPR
    bool work;
    float own[8];         // residual slab
    float nb[4][8];       // neighbor slabs (this thread's pixel)
    float tr[4][6];       // r00 r01 w03 r10 r11 w13  (uniform, SGPR via rfl)
};

// Issue all global loads for item `idx`; values land later (regs), hidden by
// the previous item's gather phase.
static __device__ __forceinline__ Item prefetch_item(
        const float* __restrict__ feat, const float* __restrict__ trans,
        const int* __restrict__ numa, int idx, int p) {
    Item it;
    const int g = idx & 63;
    const int r = idx >> 6;
    it.i = r % NA;
    it.b = r / NA;
    it.c0 = g << 3;
    it.n = numa[it.b * NA];
    it.work = (it.i < it.n) && (it.n > 1);
    const float* own = feat + ((it.i * NB + it.b) * NC + it.c0) * HW + p;
#pragma unroll
    for (int k = 0; k < 8; ++k) it.own[k] = own[k * HW];
    if (it.work) {
#pragma unroll
        for (int jj = 0; jj < 4; ++jj) {
            const int j = jj + (jj >= it.i);
            if (j < it.n) {                    // block-uniform
                const float* tw = trans + (((it.b * NA) + it.i) * NA + j) * 16;
                it.tr[jj][0] = rfl(tw[0]);     // r00
                it.tr[jj][1] = rfl(tw[1]);     // r01
                it.tr[jj][2] = rfl(tw[3]);     // w03 (tx source)
                it.tr[jj][3] = rfl(tw[4]);     // r10
                it.tr[jj][4] = rfl(tw[5]);     // r11
                it.tr[jj][5] = rfl(tw[7]);     // w13 (ty source)
                const float* src = feat + ((j * NB + it.b) * NC + it.c0) * HW + p;
#pragma unroll
                for (int k = 0; k < 8; ++k) it.nb[jj][k] = src[k * HW];
            }
        }
    }
    return it;
}

// Two-phase gather: phase A computes feat_rot ONCE per pixel (the old kernel
// recomputed it at all 4 stage-2 tap positions -> 4x redundant bilinears,
// 16 LDS reads/pair); phase B applies the pair-uniform 2x2 translation
// stencil from the rot buffer (4 LDS reads/pair) with f32 accumulation.
__global__ __launch_bounds__(256, 4) void fafmimo_twophase_kernel(
    const float* __restrict__ feat,   // [A*B][C][256], feat[a*B+b] = local[b][a]
    const float* __restrict__ trans,  // [B][A][A][4][4]
    const int*   __restrict__ numa,   // [B][A], use [:,0]
    float*       __restrict__ out)    // [A*B][C][256]
{
    __shared__ h8 lds_nb[4][HW];      // 16 KiB  staged neighbor slabs
    __shared__ h8 lds_rot[4][HW];     // 16 KiB  rotated intermediates

    const int p = threadIdx.x;
    const int x = p & 15, y = p >> 4;
    const float fx = (float)x - 7.5f;
    const float fy = (float)y - 7.5f;
    bool dirty = false;               // block-uniform

    int idx = blockIdx.x;
    Item cur = prefetch_item(feat, trans, numa, idx, p);

    while (true) {
        // ---- LDS stage phase for cur ----
        if (cur.work) {
            if (dirty) __syncthreads();       // prior item's LDS readers done
#pragma unroll
            for (int jj = 0; jj < 4; ++jj) {
                const int j = jj + (jj >= cur.i);
                if (j < cur.n) {
                    h8 v;
#pragma unroll
                    for (int k = 0; k < 8; ++k) v[k] = (_Float16)cur.nb[jj][k];
                    lds_nb[jj][p] = v;
                }
            }
            __syncthreads();
            dirty = true;
        }

        // ---- prefetch next item (loads overlap phases A/B below) ----
        const int nidx = idx + NBLK;
        const bool more = nidx < NTOT;        // block-uniform
        Item nxt;
        if (more) nxt = prefetch_item(feat, trans, numa, nidx, p);

        float acc[8];
#pragma unroll
        for (int k = 0; k < 8; ++k) acc[k] = cur.own[k];

        if (cur.work) {
            // ---- Phase A: rotation bilinear at this thread's own pixel ----
#pragma unroll
            for (int jj = 0; jj < 4; ++jj) {
                const int j = jj + (jj >= cur.i);
                if (j < cur.n) {
                    const float bx = cur.tr[jj][0] * fx + cur.tr[jj][1] * fy + 7.5f;
                    const float by = cur.tr[jj][3] * fx + cur.tr[jj][4] * fy + 7.5f;
                    const float fbx = floorf(bx), fby = floorf(by);
                    const int ix = (int)fbx, iy = (int)fby;
                    const float wx1 = bx - fbx, wy1 = by - fby;
                    const float mx0 = (ix     >= 0 && ix     < 16) ? 1.0f - wx1 : 0.0f;
                    const float mx1 = (ix + 1 >= 0 && ix + 1 < 16) ? wx1 : 0.0f;
                    const float my0 = (iy     >= 0 && iy     < 16) ? 1.0f - wy1 : 0.0f;
                    const float my1 = (iy + 1 >= 0 && iy + 1 < 16) ? wy1 : 0.0f;
                    const int cx0 = min(max(ix, 0), 15), cx1 = min(max(ix + 1, 0), 15);
                    const int cy0 = min(max(iy, 0), 15), cy1 = min(max(iy + 1, 0), 15);
                    const h8 v00 = lds_nb[jj][cy0 * 16 + cx0];
                    const h8 v01 = lds_nb[jj][cy0 * 16 + cx1];
                    const h8 v10 = lds_nb[jj][cy1 * 16 + cx0];
                    const h8 v11 = lds_nb[jj][cy1 * 16 + cx1];
                    lds_rot[jj][p] =
                          v00 * splat8(mx0 * my0) + v01 * splat8(mx1 * my0)
                        + v10 * splat8(mx0 * my1) + v11 * splat8(mx1 * my1);
                }
            }
            __syncthreads();

            // ---- Phase B: pair-uniform 2x2 translation stencil ----
#pragma unroll
            for (int jj = 0; jj < 4; ++jj) {
                const int j = jj + (jj >= cur.i);
                if (j < cur.n) {
                    // all of this block is wave-uniform (SGPR) except ox/oy/masks
                    const float dx = 0.25f * cur.tr[jj][2];
                    const float dy = -0.25f * cur.tr[jj][5];
                    const float fdx = floorf(dx), fdy = floorf(dy);
                    const float tx1 = dx - fdx, tx0 = 1.0f - tx1;
                    const float ty1 = dy - fdy, ty0 = 1.0f - ty1;
                    const int ox = x + (int)fdx;
                    const int oy = y + (int)fdy;
                    const bool inx0 = (ox     >= 0) && (ox     < 16);
                    const bool inx1 = (ox + 1 >= 0) && (ox + 1 < 16);
                    const bool iny0 = (oy     >= 0) && (oy     < 16);
                    const bool iny1 = (oy + 1 >= 0) && (oy + 1 < 16);
                    const float w00 = (inx0 && iny0) ? tx0 * ty0 : 0.0f;
                    const float w10 = (inx1 && iny0) ? tx1 * ty0 : 0.0f;
                    const float w01 = (inx0 && iny1) ? tx0 * ty1 : 0.0f;
                    const float w11 = (inx1 && iny1) ? tx1 * ty1 : 0.0f;
                    const int cx0 = min(max(ox, 0), 15), cx1 = min(max(ox + 1, 0), 15);
                    const int cy0 = min(max(oy, 0), 15), cy1 = min(max(oy + 1, 0), 15);
                    const h8 t00 = lds_rot[jj][cy0 * 16 + cx0];
                    const h8 t01 = lds_rot[jj][cy0 * 16 + cx1];
                    const h8 t10 = lds_rot[jj][cy1 * 16 + cx0];
                    const h8 t11 = lds_rot[jj][cy1 * 16 + cx1];
                    const h8 s = t00 * splat8(w00) + t01 * splat8(w10)
                               + t10 * splat8(w01) + t11 * splat8(w11);
#pragma unroll
                    for (int k = 0; k < 8; ++k) acc[k] += (float)s[k];  // f32 accum
                }
            }
        }

        float* dst = out + ((cur.i * NB + cur.b) * NC + cur.c0) * HW + p;
#pragma unroll
        for (int k = 0; k < 8; ++k) dst[k * HW] = acc[k];

        if (!more) break;
        cur = nxt;
        idx = nidx;
    }
}

extern "C" void kernel_launch(void* const* d_in, const int* in_sizes, int n_in,
                              void* d_out, int out_size, void* d_ws, size_t ws_size,
                              hipStream_t stream) {
    const float* feat  = (const float*)d_in[0];
    const float* trans = (const float*)d_in[1];
    const int*   numa  = (const int*)d_in[2];
    float* out = (float*)d_out;

    fafmimo_twophase_kernel<<<dim3(NBLK), dim3(256), 0, stream>>>(
        feat, trans, numa, out);
}